// Round 4
// baseline (354.179 us; speedup 1.0000x reference)
//
#include <hip/hip_runtime.h>
#include <cstdint>
#include <cstddef>

#define NE 16
#define TOPK 6
#define HID 1024
#define NTOK 8192
#define EPSF 1e-10f
#define CAP_ROWS 51200   // Y capacity: 400 * 128 (worst-case 128-padded rows)
#define MAXB256 208      // worst-case 256-row mblocks: (400+16)/2
#define NT 16            // K tiles of 64 (1024/64)
#define ROUTER_BLKS 2048 // NTOK/4
#define BUFB 49152       // bytes per LDS tile buffer: A 32KB + B 16KB

typedef short bf16x8 __attribute__((ext_vector_type(8)));
typedef float f32x4 __attribute__((ext_vector_type(4)));

__device__ __forceinline__ unsigned int f2bf_rne(float f) {
  union { float f; unsigned int u; } v;
  v.f = f;
  return (v.u + 0x7FFFu + ((v.u >> 16) & 1u)) >> 16;
}

__device__ __forceinline__ float bfbits2f(unsigned int hi16) {
  union { unsigned int u; float f; } v;
  v.u = hi16 << 16;
  return v.f;
}

__device__ __forceinline__ void load_lds16(const void* g, void* l) {
  __builtin_amdgcn_global_load_lds(
      (const __attribute__((address_space(1))) void*)g,
      (__attribute__((address_space(3))) void*)l, 16, 0, 0);
}

// fused independent pre-work:
//   blocks [0, ROUTER_BLKS): router (LDS-free; rw read direct, L2-hot) -
//     logits -> softmax -> top6; fuses X f32->bf16 conversion.
//   blocks [ROUTER_BLKS, +4096): W f32 [e][k][n] -> bf16 transposed [e][n][k].
__global__ __launch_bounds__(256) void fused_pre_kernel(
    const float* __restrict__ tokens, const float* __restrict__ rw,
    const float* __restrict__ rb, unsigned short* __restrict__ Xb,
    unsigned int* __restrict__ topk, float* __restrict__ g6,
    float* __restrict__ epst, const float* __restrict__ ew,
    unsigned short* __restrict__ wt) {
  __shared__ float tile[64][65];
  const int tid = threadIdx.x;
  const unsigned bx = blockIdx.x;

  if (bx >= ROUTER_BLKS) {
    // ---- cvt_wt body ----
    const int q = bx - ROUTER_BLKS;
    const int e2 = q >> 8;
    const int ntile = ((q >> 4) & 15) * 64;
    const int ktile = (q & 15) * 64;
    const int tr = tid >> 6;
    const int tc = tid & 63;
    const float* wp = ew + (size_t)e2 * HID * HID;
#pragma unroll
    for (int r = 0; r < 64; r += 4)
      tile[r + tr][tc] = wp[(size_t)(ktile + r + tr) * HID + ntile + tc];
    __syncthreads();
    unsigned short* wo = wt + (size_t)e2 * HID * HID;
    const int aa = tid & 31;   // k-pair index
    const int rg = tid >> 5;   // row-in-group 0..7
#pragma unroll
    for (int c2 = 0; c2 < 64; c2 += 8) {
      const int n = c2 + rg;
      const unsigned lo = f2bf_rne(tile[2 * aa][n]);
      const unsigned hi = f2bf_rne(tile[2 * aa + 1][n]);
      *(unsigned int*)(wo + (size_t)(ntile + n) * HID + ktile + 2 * aa) =
          lo | (hi << 16);
    }
    return;
  }

  // ---- router body ----
  const int wv = tid >> 6;
  const int lane = tid & 63;
  const int token = (int)bx * 4 + wv;

  const float4* xp4 = (const float4*)(tokens + (size_t)token * HID);
  float4 x4[4];
#pragma unroll
  for (int j = 0; j < 4; ++j) x4[j] = xp4[lane + 64 * j];

  unsigned short* xbrow = Xb + (size_t)token * HID;
#pragma unroll
  for (int j = 0; j < 4; ++j) {
    const unsigned lo = f2bf_rne(x4[j].x) | (f2bf_rne(x4[j].y) << 16);
    const unsigned hi = f2bf_rne(x4[j].z) | (f2bf_rne(x4[j].w) << 16);
    *(uint2*)(xbrow + 4 * (lane + 64 * j)) = (uint2){lo, hi};
  }

  float lg[NE];
#pragma unroll
  for (int e = 0; e < NE; ++e) {
    const float4* wp4 = (const float4*)(rw + e * HID);
    float p = 0.f;
#pragma unroll
    for (int j = 0; j < 4; ++j) {
      const float4 w = wp4[lane + 64 * j];
      p += x4[j].x * w.x + x4[j].y * w.y + x4[j].z * w.z + x4[j].w * w.w;
    }
    lg[e] = p;
  }
#pragma unroll
  for (int m = 1; m < 64; m <<= 1) {
#pragma unroll
    for (int e = 0; e < NE; ++e) lg[e] += __shfl_xor(lg[e], m);
  }
  float mx = -1e30f;
#pragma unroll
  for (int e = 0; e < NE; ++e) {
    lg[e] += rb[e];
    mx = fmaxf(mx, lg[e]);
  }
  float q[NE];
  float s_all = 0.f;
#pragma unroll
  for (int e = 0; e < NE; ++e) {
    q[e] = expf(lg[e] - mx);
    s_all += q[e];
  }
  unsigned sel = 0, pack = 0;
  float s_top = 0.f;
  float gq[TOPK];
#pragma unroll
  for (int k = 0; k < TOPK; ++k) {
    float best = -1.f;
    int bi = 0;
#pragma unroll
    for (int e = 0; e < NE; ++e) {
      bool taken = (sel >> e) & 1u;
      if (!taken && q[e] > best) { best = q[e]; bi = e; }
    }
    sel |= 1u << bi;
    gq[k] = best;
    s_top += best;
    pack |= ((unsigned)bi) << (4 * k);
  }
  if (lane < TOPK)
    g6[(size_t)token * TOPK + lane] = gq[lane] / s_top;
  if (lane == 32) {
    topk[token] = pack;
    float s = s_top / s_all;
    epst[token] = EPSF * (s / (s + EPSF));
  }
}

// sortassign, atomic-free, 4 barriers. 16 blocks x 1024 threads.
// Also zeroes the 8 per-XCD work counters for the dynamic ggemm scheduler.
__global__ __launch_bounds__(1024) void sortassign_kernel(
    const unsigned int* __restrict__ topk, const float* __restrict__ g6,
    unsigned int* __restrict__ tokmap, float* __restrict__ gpos,
    unsigned int* __restrict__ inv, unsigned int* __restrict__ table,
    unsigned int* __restrict__ total, unsigned int* __restrict__ xcdctr) {
  __shared__ unsigned int sred[NE][65];
  __shared__ unsigned int s_seg[NE];
  __shared__ unsigned int hist[NE];
  __shared__ unsigned int wofs[16];
  const int e = blockIdx.x;
  const int tid = threadIdx.x;
  const int lane = tid & 63;
  const int wvid = tid >> 6;

  if (e == 0 && tid < 8) xcdctr[tid] = 0u;

  // full 16-expert histogram (needed for segment offsets on every block)
  {
    const unsigned hx = tid & 15u;
    const int hc = tid >> 4;
    const unsigned int* tp = topk + hc * 128;
    unsigned hcnt = 0;
    for (int i = 0; i < 128; ++i) {
      const unsigned p = tp[i];
#pragma unroll
      for (int k = 0; k < TOPK; ++k) hcnt += (((p >> (4 * k)) & 15u) == hx);
    }
    sred[hx][hc] = hcnt;
  }
  __syncthreads();
  if (tid < NE) {
    unsigned s = 0;
    for (int jj = 0; jj < 64; ++jj) s += sred[tid][jj];
    hist[tid] = s;
  }
  __syncthreads();
  if (tid == 0) {
    unsigned off = 0;
    for (int i = 0; i < NE; ++i) {
      s_seg[i] = off;
      off += ((hist[i] + 127) >> 7) << 7;
    }
    if (e == 0) {
      unsigned b = 0;
      for (int i = 0; i < NE; ++i) {
        const unsigned nb = (hist[i] + 127) >> 7;
        const unsigned seg = s_seg[i];
        unsigned m = 0;
        for (; m + 2 <= nb; m += 2)
          table[b++] = ((unsigned)i << 24) | (seg + m * 128);
        if (m < nb)
          table[b++] = ((unsigned)i << 24) | (1u << 23) | (seg + m * 128);
      }
      *total = b;
    }
  }

  // per-thread count of expert e over its 8-token chunk
  const int tbase = tid * (NTOK / 1024);
  unsigned c = 0;
  for (int i = 0; i < NTOK / 1024; ++i) {
    const unsigned p = topk[tbase + i];
#pragma unroll
    for (int k = 0; k < TOPK; ++k) c += (((p >> (4 * k)) & 15u) == (unsigned)e);
  }
  unsigned pfx = c;
#pragma unroll
  for (int m = 1; m < 64; m <<= 1) {
    const unsigned v = __shfl_up(pfx, m);
    if (lane >= m) pfx += v;
  }
  if (lane == 63) wofs[wvid] = pfx;
  __syncthreads();
  if (tid == 0) {
    unsigned r = 0;
    for (int i = 0; i < 16; ++i) { const unsigned t = wofs[i]; wofs[i] = r; r += t; }
  }
  __syncthreads();

  const unsigned seg0 = s_seg[e];
  unsigned pos = seg0 + wofs[wvid] + (pfx - c);
  for (int i = 0; i < NTOK / 1024; ++i) {
    const int t = tbase + i;
    const unsigned p = topk[t];
#pragma unroll
    for (int k = 0; k < TOPK; ++k) {
      if (((p >> (4 * k)) & 15u) == (unsigned)e) {
        tokmap[pos] = (unsigned)t;
        gpos[pos] = g6[(size_t)t * TOPK + k];
        inv[(size_t)t * TOPK + k] = pos;
        ++pos;
      }
    }
  }
  const unsigned cnt_e = hist[e];
  const unsigned segend = seg0 + (((cnt_e + 127) >> 7) << 7);
  for (unsigned p2 = seg0 + cnt_e + tid; p2 < segend; p2 += 1024) {
    tokmap[p2] = 0u;
    gpos[p2] = 0.f;
  }
}

// PERSISTENT grouped GEMM v2: 256x128 tile, BK=64, TRIPLE-buffered LDS
// (stage tile t+2 while computing t -> every load has ~2 K-tiles of slack
// before its vmcnt(6) gate; one gate per K-tile, never 0). ks-split phases
// (2/K-tile): each 16-MFMA cluster hits 16 distinct accs (no dep pairs),
// reads balanced 8/8, barriers halved. Dynamic per-XCD atomic scheduler at
// 128-col strips (nwg = tot*8, exactly tot per XCD) kills the static-chunk
// tail. Swizzle (verified, 0 conflicts) unchanged: pre-swizzled global src
// + XOR on ds_read.
__global__ __launch_bounds__(512, 2) void moe_ggemm_kernel(
    const unsigned short* __restrict__ Xb, const unsigned short* __restrict__ Wt,
    const unsigned int* __restrict__ table, const unsigned int* __restrict__ total,
    const unsigned int* __restrict__ tokmap, const float* __restrict__ gpos,
    unsigned short* __restrict__ Y, unsigned int* __restrict__ xcdctr) {
  __shared__ char Buf[3 * BUFB];
  __shared__ float Gs[2][256];
  __shared__ unsigned int s_i0;
  __shared__ unsigned int s_nxt;

  const int tid = threadIdx.x;
  const unsigned tot = *total;
  const unsigned xcd = blockIdx.x & 7u;

  if (tid == 0) s_i0 = atomicAdd(&xcdctr[xcd], 1u);
  __syncthreads();
  if (s_i0 >= tot) return;
  unsigned w = xcd * tot + s_i0;

  const int wv = tid >> 6;
  const int lane = tid & 63;
  const int lm = lane & 15;
  const int quad = lane >> 4;
  const int mg = wv >> 1;                 // M-group 0..3 (64 rows each)
  const int woff_m = mg * 64;
  const int woff_n = (wv & 1) * 64;       // N-group 0..1
  const int srow = tid >> 3;              // 0..63
  const int scol = ((tid & 7) ^ (srow & 7)) << 4;  // pre-swizzled source col
  const int sdst = wv * 1024;             // wave-uniform dest in 8KB instr blk
  const int rsw = (lm & 7) << 4;
  const int o0 = (quad * 16) ^ rsw;       // ks=0 in-row offset (swizzled)
  const int o1 = (64 + quad * 16) ^ rsw;  // ks=1

  // ---- current-slot meta ----
  unsigned ent = table[w >> 3];
  int e = (int)(ent >> 24);
  int half = (int)((ent >> 23) & 1u);
  int row0 = (int)(ent & 0x7FFFFFu);
  int n0 = (int)(w & 7u) * 128;
  const char* pA[4];
  const char* pB[2];
#pragma unroll
  for (int i = 0; i < 4; ++i) {
    const int r = i * 64 + srow;
    const int rc = (half && r >= 128) ? 127 : r;
    pA[i] = (const char*)Xb + (size_t)tokmap[row0 + rc] * (HID * 2) + scol;
  }
#pragma unroll
  for (int j = 0; j < 2; ++j)
    pB[j] = (const char*)Wt + (size_t)e * (HID * HID * 2) +
            (size_t)(n0 + j * 64 + srow) * (HID * 2) + scol;
  if (tid < 256)
    Gs[0][tid] = gpos[row0 + ((half && tid >= 128) ? 127 : tid)];
  if (tid == 0) s_nxt = atomicAdd(&xcdctr[xcd], 1u);
  __syncthreads();
  unsigned nxt = s_nxt;

  // ---- prologue: stage tiles 0,1 into Buf[0],Buf[1] ----
#pragma unroll
  for (int t = 0; t < 2; ++t) {
    char* bb = Buf + t * BUFB;
    const int ko = t * 128;
    load_lds16(pA[0] + ko, bb + 0 * 8192 + sdst);
    load_lds16(pA[1] + ko, bb + 1 * 8192 + sdst);
    load_lds16(pA[2] + ko, bb + 2 * 8192 + sdst);
    load_lds16(pA[3] + ko, bb + 3 * 8192 + sdst);
    load_lds16(pB[0] + ko, bb + 32768 + 0 * 8192 + sdst);
    load_lds16(pB[1] + ko, bb + 32768 + 8192 + sdst);
  }
  asm volatile("s_waitcnt vmcnt(6)" ::: "memory");
  __builtin_amdgcn_s_barrier();

  f32x4 acc[4][4];
#pragma unroll
  for (int f = 0; f < 4; ++f)
#pragma unroll
    for (int n = 0; n < 4; ++n) acc[f][n] = (f32x4){0.f, 0.f, 0.f, 0.f};

  int gp = 0;
  int bufc = 0;

  while (true) {
    // ---- next-slot meta + early gathers (older-than-stage in vmcnt queue:
    // gates drain them harmlessly; all L2-fast) ----
    const unsigned wN = (nxt < tot) ? (xcd * tot + nxt) : w;
    const unsigned entN = table[wN >> 3];
    const int eN = (int)(entN >> 24);
    const int halfN = (int)((entN >> 23) & 1u);
    const int row0N = (int)(entN & 0x7FFFFFu);
    const int n0N = (int)(wN & 7u) * 128;
    const char* nA[4];
    const char* nB[2];
#pragma unroll
    for (int i = 0; i < 4; ++i) {
      const int r = i * 64 + srow;
      const int rc = (halfN && r >= 128) ? 127 : r;
      nA[i] = (const char*)Xb + (size_t)tokmap[row0N + rc] * (HID * 2) + scol;
    }
#pragma unroll
    for (int j = 0; j < 2; ++j)
      nB[j] = (const char*)Wt + (size_t)eN * (HID * HID * 2) +
              (size_t)(n0N + j * 64 + srow) * (HID * 2) + scol;
    if (tid < 256)
      Gs[gp ^ 1][tid] = gpos[row0N + ((halfN && tid >= 128) ? 127 : tid)];
    if (tid == 0) s_nxt = atomicAdd(&xcdctr[xcd], 1u);

    for (int kt = 0; kt < NT; ++kt) {
      char* cur = Buf + bufc * BUFB;
      int sb = bufc + 2; if (sb >= 3) sb -= 3;
      char* stg = Buf + sb * BUFB;

      // stage sources: tile kt+2 of cur slot; kt=14,15 -> next slot tiles 0,1
      const char *sA0, *sA1, *sA2, *sA3, *sB0, *sB1;
      if (kt < NT - 2) {
        const int ko = (kt + 2) * 128;
        sA0 = pA[0] + ko; sA1 = pA[1] + ko; sA2 = pA[2] + ko; sA3 = pA[3] + ko;
        sB0 = pB[0] + ko; sB1 = pB[1] + ko;
      } else {
        const int ko = (kt - (NT - 2)) * 128;
        sA0 = nA[0] + ko; sA1 = nA[1] + ko; sA2 = nA[2] + ko; sA3 = nA[3] + ko;
        sB0 = nB[0] + ko; sB1 = nB[1] + ko;
      }

      bf16x8 a[4], b[4];

      // -------- P0 (ks=0): 8 reads, stage A0-A2, 16 indep MFMA
#pragma unroll
      for (int f = 0; f < 4; ++f)
        a[f] = *(const bf16x8*)(cur + (woff_m + 16 * f + lm) * 128 + o0);
#pragma unroll
      for (int n = 0; n < 4; ++n)
        b[n] = *(const bf16x8*)(cur + 32768 + (woff_n + 16 * n + lm) * 128 + o0);
      load_lds16(sA0, stg + 0 * 8192 + sdst);
      load_lds16(sA1, stg + 1 * 8192 + sdst);
      load_lds16(sA2, stg + 2 * 8192 + sdst);
      __builtin_amdgcn_s_barrier();
      asm volatile("s_waitcnt lgkmcnt(0)" ::: "memory");
      __builtin_amdgcn_s_setprio(1);
#pragma unroll
      for (int f = 0; f < 4; ++f)
#pragma unroll
        for (int n = 0; n < 4; ++n)
          acc[f][n] = __builtin_amdgcn_mfma_f32_16x16x32_bf16(a[f], b[n], acc[f][n], 0, 0, 0);
      __builtin_amdgcn_s_setprio(0);
      __builtin_amdgcn_s_barrier();

      // -------- P1 (ks=1): 8 reads, stage A3,B0,B1, 16 MFMA, gate vmcnt(6)
#pragma unroll
      for (int f = 0; f < 4; ++f)
        a[f] = *(const bf16x8*)(cur + (woff_m + 16 * f + lm) * 128 + o1);
#pragma unroll
      for (int n = 0; n < 4; ++n)
        b[n] = *(const bf16x8*)(cur + 32768 + (woff_n + 16 * n + lm) * 128 + o1);
      load_lds16(sA3, stg + 3 * 8192 + sdst);
      load_lds16(sB0, stg + 32768 + 0 * 8192 + sdst);
      load_lds16(sB1, stg + 32768 + 8192 + sdst);
      __builtin_amdgcn_s_barrier();
      asm volatile("s_waitcnt lgkmcnt(0)" ::: "memory");
      __builtin_amdgcn_s_setprio(1);
#pragma unroll
      for (int f = 0; f < 4; ++f)
#pragma unroll
        for (int n = 0; n < 4; ++n)
          acc[f][n] = __builtin_amdgcn_mfma_f32_16x16x32_bf16(a[f], b[n], acc[f][n], 0, 0, 0);
      __builtin_amdgcn_s_setprio(0);
      // tile kt+1 (staged last K-tile) must be landed; tile kt+2's 6 stay out
      asm volatile("s_waitcnt vmcnt(6)" ::: "memory");
      __builtin_amdgcn_s_barrier();

      bufc += 1; if (bufc >= 3) bufc = 0;
    }

    // ---- epilogue: 64 bf16 stores/thread; next-slot tiles 0,1 in flight ----
    if (!(half && mg >= 2)) {
      const float* gsl = &Gs[gp][0];
#pragma unroll
      for (int f = 0; f < 4; ++f)
#pragma unroll
        for (int r = 0; r < 4; ++r) {
          const int row = woff_m + 16 * f + quad * 4 + r;
          const float gte = gsl[row];
          unsigned short* yrow = Y + (size_t)(row0 + row) * HID + n0;
#pragma unroll
          for (int n = 0; n < 4; ++n)
            yrow[woff_n + 16 * n + lm] = (unsigned short)f2bf_rne(gte * acc[f][n][r]);
        }
    }
    if (wN == w) break;

    __syncthreads();  // Gs[gp] reads done before next iter overwrites; s_nxt ready
    nxt = s_nxt;
    w = wN; e = eN; half = halfN; row0 = row0N; n0 = n0N;
#pragma unroll
    for (int i = 0; i < 4; ++i) pA[i] = nA[i];
#pragma unroll
    for (int j = 0; j < 2; ++j) pB[j] = nB[j];
    gp ^= 1;
#pragma unroll
    for (int f = 0; f < 4; ++f)
#pragma unroll
      for (int n = 0; n < 4; ++n) acc[f][n] = (f32x4){0.f, 0.f, 0.f, 0.f};
  }

  asm volatile("s_waitcnt vmcnt(0)" ::: "memory");
}

// reduce: out[t,:] = sum_k Y[inv[t,k],:] + eps[t].  2 tokens/block.
__global__ __launch_bounds__(256) void reduce_kernel(
    const unsigned short* __restrict__ Y, const unsigned int* __restrict__ inv,
    const float* __restrict__ epst, float* __restrict__ out) {
  const int sub = threadIdx.x >> 7;
  const int ct = threadIdx.x & 127;
  const int t = blockIdx.x * 2 + sub;
  const int c0 = ct * 8;

  float s[8];
  const float ep = epst[t];
#pragma unroll
  for (int i = 0; i < 8; ++i) s[i] = ep;

#pragma unroll
  for (int k = 0; k < TOPK; ++k) {
    const unsigned pos = inv[(size_t)t * TOPK + k];
    const uint4 v = *(const uint4*)(Y + (size_t)pos * HID + c0);
    s[0] += bfbits2f(v.x & 0xFFFFu);
    s[1] += bfbits2f(v.x >> 16);
    s[2] += bfbits2f(v.y & 0xFFFFu);
    s[3] += bfbits2f(v.y >> 16);
    s[4] += bfbits2f(v.z & 0xFFFFu);
    s[5] += bfbits2f(v.z >> 16);
    s[6] += bfbits2f(v.w & 0xFFFFu);
    s[7] += bfbits2f(v.w >> 16);
  }
  float* orow = out + (size_t)t * HID + c0;
  *(float4*)orow = (float4){s[0], s[1], s[2], s[3]};
  *(float4*)(orow + 4) = (float4){s[4], s[5], s[6], s[7]};
}

extern "C" void kernel_launch(void* const* d_in, const int* in_sizes, int n_in,
                              void* d_out, int out_size, void* d_ws, size_t ws_size,
                              hipStream_t stream) {
  const float* tokens = (const float*)d_in[0];  // [4,2048,1024] f32
  const float* rw = (const float*)d_in[1];      // [16,1024] f32
  const float* rb = (const float*)d_in[2];      // [16] f32
  const float* ew = (const float*)d_in[3];      // [16,1024,1024] f32
  float* out = (float*)d_out;                   // [4,2048,1024] f32

  char* ws = (char*)d_ws;
  const size_t OFF_XB = 0;                        // 16 MB
  const size_t OFF_WT = 16777216;                 // 32 MB
  const size_t OFF_Y = 50331648;                  // 100 MB (51200 x 1024 bf16)
  const size_t OFF_META = 155189248;
  const size_t M_TOKMAP = OFF_META + 0;           // 51200 u32
  const size_t M_GPOS = OFF_META + 204800;        // 51200 f32
  const size_t M_TOTAL = OFF_META + 409600;       // 1 u32 (pad 64)
  const size_t M_TABLE = OFF_META + 409664;       // 400 u32 (pad)
  const size_t M_INV = OFF_META + 411328;         // 49152 u32
  const size_t M_TOPK = OFF_META + 607936;        // 8192 u32
  const size_t M_G6 = OFF_META + 640704;          // 49152 f32
  const size_t M_EPST = OFF_META + 837312;        // 8192 f32
  const size_t M_XCDC = OFF_META + 870080;        // 8 u32 work counters

  unsigned short* Xb = (unsigned short*)(ws + OFF_XB);
  unsigned short* Wt = (unsigned short*)(ws + OFF_WT);
  unsigned short* Y = (unsigned short*)(ws + OFF_Y);
  unsigned int* tokmap = (unsigned int*)(ws + M_TOKMAP);
  float* gpos = (float*)(ws + M_GPOS);
  unsigned int* total = (unsigned int*)(ws + M_TOTAL);
  unsigned int* table = (unsigned int*)(ws + M_TABLE);
  unsigned int* inv = (unsigned int*)(ws + M_INV);
  unsigned int* topk = (unsigned int*)(ws + M_TOPK);
  float* g6 = (float*)(ws + M_G6);
  float* epst = (float*)(ws + M_EPST);
  unsigned int* xcdctr = (unsigned int*)(ws + M_XCDC);

  fused_pre_kernel<<<dim3(ROUTER_BLKS + (HID / 64) * (HID / 64) * NE), dim3(256),
                     0, stream>>>(tokens, rw, rb, Xb, topk, g6, epst, ew, Wt);
  sortassign_kernel<<<dim3(NE), dim3(1024), 0, stream>>>(
      topk, g6, tokmap, gpos, inv, table, total, xcdctr);
  moe_ggemm_kernel<<<dim3(256), dim3(512), 0, stream>>>(
      Xb, Wt, table, total, tokmap, gpos, Y, xcdctr);
  reduce_kernel<<<dim3(NTOK / 2), dim3(256), 0, stream>>>(Y, inv, epst, out);
}